// Round 11
// baseline (58.287 us; speedup 1.0000x reference)
//
#include <hip/hip_runtime.h>

#define THREADS 512
#define PI_F 3.14159265358979323846f
#define RT2O2 0.70710678118654752440f

// Complex as native 2-float vector -> packed fp32 (v_pk_add/fma_f32).
typedef float cpx __attribute__((ext_vector_type(2)));

__device__ __forceinline__ cpx cmul(cpx a, cpx b) {
    cpx r = cpx{a.x, a.x} * b;
    return r + cpx{-a.y, a.y} * cpx{b.y, b.x};
}
__device__ __forceinline__ cpx mulni(cpx a) { return cpx{a.y, -a.x}; }   // * (-i)
__device__ __forceinline__ cpx mulpi(cpx a) { return cpx{-a.y, a.x}; }   // * (+i)

// XOR swizzle on cpx index (8B units): bits [3:1] ^= (bits[6:4]^bits[10:8]).
// Bit 0 untouched -> cpx-pair (float4) contiguity preserved.
__device__ __forceinline__ int SW(int i) { return i ^ ((((i >> 4) ^ (i >> 8)) & 7) << 1); }

__device__ __forceinline__ cpx ldb(const cpx* b, int i) { return b[SW(i)]; }
__device__ __forceinline__ void stb(cpx* b, int i, cpx v) { b[SW(i)] = v; }

// cos/sin(pi*i/8) and cos/sin(pi*i/32), i = 0..7 (compile-time folded).
constexpr float C8[8] = {1.f, 0.92387953251128674f, RT2O2, 0.38268343236508978f,
                         0.f, -0.38268343236508978f, -RT2O2, -0.92387953251128674f};
constexpr float S8[8] = {0.f, 0.38268343236508978f, RT2O2, 0.92387953251128674f,
                         1.f, 0.92387953251128674f, RT2O2, 0.38268343236508978f};
constexpr float C32[8] = {1.f, 0.99518472667219693f, 0.98078528040323044f, 0.95694033573220886f,
                          0.92387953251128674f, 0.88192126434835503f, 0.83146961230254524f, 0.77301045336273699f};
constexpr float S32[8] = {0.f, 0.09801714032956060f, 0.19509032201612827f, 0.29028467725446233f,
                          0.38268343236508978f, 0.47139673682599764f, 0.55557023301960222f, 0.63439328416364549f};

// In-place 8-point DFT (DIF), natural order in/out: z[s] = sum_n z[n] W8^{ns}
__device__ __forceinline__ void dft8(cpx* z) {
    cpx e0 = z[0] + z[4], e1 = z[1] + z[5], e2 = z[2] + z[6], e3 = z[3] + z[7];
    cpx o0 = z[0] - z[4], o1 = z[1] - z[5], o2 = z[2] - z[6], o3 = z[3] - z[7];
    o1 = cmul(o1, cpx{RT2O2, -RT2O2});   // * W8^1
    o2 = mulni(o2);                       // * W8^2
    o3 = cmul(o3, cpx{-RT2O2, -RT2O2});  // * W8^3
    cpx a0 = e0 + e2, a1 = e1 + e3, b0 = e0 - e2, b1 = e1 - e3;
    z[0] = a0 + a1; z[4] = a0 - a1;
    z[2] = b0 + mulni(b1); z[6] = b0 + mulpi(b1);
    cpx c0 = o0 + o2, c1 = o1 + o3, d0 = o0 - o2, d1 = o1 - o3;
    z[1] = c0 + c1; z[5] = c0 - c1;
    z[3] = d0 + mulni(d1); z[7] = d0 + mulpi(d1);
}

// z[s] *= w1^s, s=1..7; powers via squaring tree (dep depth 3).
__device__ __forceinline__ void twiddle8(cpx* z, float theta) {
    float s_, c_;
    __sincosf(theta, &s_, &c_);
    cpx w1 = {c_, s_};
    cpx w2 = cmul(w1, w1), w3 = cmul(w1, w2), w4 = cmul(w2, w2);
    cpx w5 = cmul(w2, w3), w6 = cmul(w3, w3), w7 = cmul(w3, w4);
    z[1] = cmul(z[1], w1); z[2] = cmul(z[2], w2); z[3] = cmul(z[3], w3);
    z[4] = cmul(z[4], w4); z[5] = cmul(z[5], w5); z[6] = cmul(z[6], w6);
    z[7] = cmul(z[7], w7);
}

// base-8 3-digit reversal on [0,512)
__device__ __forceinline__ int R3(int x) { return ((x & 7) << 6) | (x & 56) | (x >> 6); }

// One row per 512-thread block. DST-II via N/2=4096 complex FFT, radices
// 8,8,8,8 (DIF over digits n = n0+8n1+64n2+512n3; k = u1+8u2+64u3+512u4):
//   v = Makhoul(sign*x); z[m] = v[2m] + i*v[2m+1]; Z = FFT_4096(z)
//   V[k] = Ze[k] + e^{-i pi k/4096} Zo[k]; out[8191-k] = Re(V[k] e^{-i pi k/16384})
// Stage positions in-place: idx = 512u1 + 64u2 + 8u3 + u4. S1-S3 are per-thread
// in-place (stride 512/64/8). S4: thread t handles block R3(t) (contiguous 8)
// so registers hold Z[t + 512 i] and output stores are wave-contiguous;
// Hermitian partner set Z[4096-k] lives in thread 512-t (write-back + read).
// 512 threads -> 4 blocks/CU x 8 waves = 32 waves/CU (occupancy lever vs R10).
__global__ __launch_bounds__(THREADS) void dst_fft_kernel(const float* __restrict__ x,
                                                          float* __restrict__ out) {
    __shared__ __align__(16) cpx buf[4096];  // 32 KiB

    const int row = blockIdx.x;
    const float* __restrict__ xr = x + (size_t)row * 8192;
    float* __restrict__ yr = out + (size_t)row * 8192;
    const int t = threadIdx.x;

    cpx z[8];

    // ---- load in stage-1 butterfly order: m = t + 512u ----
    // m < 2048:  z = { x[4m],        x[4m+2]      }
    // m >= 2048: z = {-x[16383-4m], -x[16381-4m]  }
#pragma unroll
    for (int u = 0; u < 4; ++u) {
        float4 f = *reinterpret_cast<const float4*>(xr + 4 * t + 2048 * u);
        z[u] = {f.x, f.z};
    }
#pragma unroll
    for (int u = 4; u < 8; ++u) {
        float4 f = *reinterpret_cast<const float4*>(xr + (16380 - 4 * t - 2048 * u));
        z[u] = {-f.w, -f.y};
    }

    // ---- stage 1: radix-8 over n3 (stride 512), twiddle W4096^{t*u1} ----
    dft8(z);
    twiddle8(z, (-2.0f * PI_F / 4096.0f) * (float)t);
#pragma unroll
    for (int i = 0; i < 8; ++i) stb(buf, t + (i << 9), z[i]);
    __syncthreads();

    // ---- stage 2: radix-8 over n2 (stride 64), twiddle W512^{(t&63)*u2} ----
    const int b2 = ((t >> 6) << 9) | (t & 63);
#pragma unroll
    for (int i = 0; i < 8; ++i) z[i] = ldb(buf, b2 + (i << 6));
    dft8(z);
    twiddle8(z, (-2.0f * PI_F / 512.0f) * (float)(t & 63));
#pragma unroll
    for (int i = 0; i < 8; ++i) stb(buf, b2 + (i << 6), z[i]);
    __syncthreads();

    // ---- stage 3: radix-8 over n1 (stride 8), twiddle W64^{(t&7)*u3} ----
    const int b3 = ((t >> 6) << 9) | (((t >> 3) & 7) << 6) | (t & 7);
#pragma unroll
    for (int i = 0; i < 8; ++i) z[i] = ldb(buf, b3 + (i << 3));
    dft8(z);
    twiddle8(z, (-2.0f * PI_F / 64.0f) * (float)(t & 7));
#pragma unroll
    for (int i = 0; i < 8; ++i) stb(buf, b3 + (i << 3), z[i]);
    __syncthreads();

    // ---- stage 4: block R3(t), contiguous 8, no twiddle; RMW + write-back ----
    const int b4 = R3(t) << 3;
#pragma unroll
    for (int w = 0; w < 4; ++w) {
        float4 v = *reinterpret_cast<const float4*>(&buf[SW(b4 + 2 * w)]);
        z[2 * w] = {v.x, v.y};
        z[2 * w + 1] = {v.z, v.w};
    }
    dft8(z);  // z[i] = Z[t + 512 i], kept in registers
#pragma unroll
    for (int w = 0; w < 4; ++w) {
        *reinterpret_cast<float4*>(&buf[SW(b4 + 2 * w)]) =
            make_float4(z[2 * w].x, z[2 * w].y, z[2 * w + 1].x, z[2 * w + 1].y);
    }
    __syncthreads();

    // ---- epilogue: partner read + real-FFT unpack + DST twiddle ----
    float s4, c4, s1, c1;
    __sincosf((PI_F / 4096.0f) * (float)t, &s4, &c4);
    __sincosf((PI_F / 16384.0f) * (float)t, &s1, &c1);
    const cpx w4 = {c4, -s4};  // e^{-i pi t/4096}
    const cpx w1 = {c1, s1};   // {cos, sin}(pi t/16384)

    // emit outputs for k = t + 512 i given Z1 = Z[k], Z2 = Z[4096-k]
    auto emit = [&](int i, cpx Z1, cpx Z2, bool writeLow) {
        const int k = t + (i << 9);
        cpx Ze = 0.5f * cpx{Z1.x + Z2.x, Z1.y - Z2.y};
        cpx Zo = 0.5f * cpx{Z1.y + Z2.y, Z2.x - Z1.x};
        cpx w4s = cmul(w4, cpx{C8[i], -S8[i]});
        cpx w1s = cmul(w1, cpx{C32[i], S32[i]});
        cpx V = Ze + cmul(w4s, Zo);
        yr[8191 - k] = fmaf(V.x, w1s.x, V.y * w1s.y);
        if (writeLow) yr[k - 1] = fmaf(V.x, w1s.y, -V.y * w1s.x);
    };

    if (t == 0) {
        // self-paired set: k = 512 i; partner reg (8-i)&7
#pragma unroll
        for (int i = 0; i < 8; ++i) emit(i, z[i], z[(8 - i) & 7], i > 0);
        yr[4095] = (z[0].x - z[0].y) * RT2O2;  // k = 4096 term
    } else {
        const int pb = R3(512 - t) << 3;
        // partner reg j' holds Z[(512-t) + 512 j']; pairing j' = 7 - i.
#pragma unroll
        for (int w = 0; w < 4; ++w) {
            float4 v = *reinterpret_cast<const float4*>(&buf[SW(pb + 2 * w)]);
            emit(7 - 2 * w, z[7 - 2 * w], cpx{v.x, v.y}, true);  // j' = 2w
            emit(6 - 2 * w, z[6 - 2 * w], cpx{v.z, v.w}, true);  // j' = 2w+1
        }
    }
}

extern "C" void kernel_launch(void* const* d_in, const int* in_sizes, int n_in,
                              void* d_out, int out_size, void* d_ws, size_t ws_size,
                              hipStream_t stream) {
    const float* x = (const float*)d_in[0];
    float* out = (float*)d_out;
    const int rows = in_sizes[0] / 8192;  // 4096
    dst_fft_kernel<<<rows, THREADS, 0, stream>>>(x, out);
}

// Round 12
// 57.251 us; speedup vs baseline: 1.0181x; 1.0181x over previous
//
#include <hip/hip_runtime.h>

#define THREADS 512
#define PI_F 3.14159265358979323846f
#define RT2O2 0.70710678118654752440f

// Complex as native 2-float vector -> packed fp32 (v_pk_add/fma_f32).
typedef float cpx __attribute__((ext_vector_type(2)));

__device__ __forceinline__ cpx cmul(cpx a, cpx b) {
    cpx r = cpx{a.x, a.x} * b;
    return r + cpx{-a.y, a.y} * cpx{b.y, b.x};
}
__device__ __forceinline__ cpx mulni(cpx a) { return cpx{a.y, -a.x}; }   // * (-i)
__device__ __forceinline__ cpx mulpi(cpx a) { return cpx{-a.y, a.x}; }   // * (+i)

// XOR swizzle on cpx index (8B units): bits [3:1] ^= bits[8:6] ^ bits[11:9].
// Sources disjoint from target -> involution; bit 0 untouched -> cpx-pair
// (float4) contiguity/alignment preserved. Chosen for the radix-8 patterns:
//   S1 (stride 512): X const per wave            -> free
//   S2 (stride 64):  X const per instruction     -> free
//   S3 (stride 8):   X = r^w varies with full r  -> uniform 4 lanes/bank-pair
//   S4/epilogue digit-reversed b128: X = m'^lq   -> uniform 8 (b128 hw min)
// (Old SW folded bits[6:4]^[10:8]; it dropped r bit 1 in S3 -> 2x conflict,
//  the 4.7e6 SQ_LDS_BANK_CONFLICT measured in R11.)
__device__ __forceinline__ int SW(int i) { return i ^ ((((i >> 6) ^ (i >> 9)) & 7) << 1); }

__device__ __forceinline__ cpx ldb(const cpx* b, int i) { return b[SW(i)]; }
__device__ __forceinline__ void stb(cpx* b, int i, cpx v) { b[SW(i)] = v; }

// cos/sin(pi*i/8) and cos/sin(pi*i/32), i = 0..7 (compile-time folded).
constexpr float C8[8] = {1.f, 0.92387953251128674f, RT2O2, 0.38268343236508978f,
                         0.f, -0.38268343236508978f, -RT2O2, -0.92387953251128674f};
constexpr float S8[8] = {0.f, 0.38268343236508978f, RT2O2, 0.92387953251128674f,
                         1.f, 0.92387953251128674f, RT2O2, 0.38268343236508978f};
constexpr float C32[8] = {1.f, 0.99518472667219693f, 0.98078528040323044f, 0.95694033573220886f,
                          0.92387953251128674f, 0.88192126434835503f, 0.83146961230254524f, 0.77301045336273699f};
constexpr float S32[8] = {0.f, 0.09801714032956060f, 0.19509032201612827f, 0.29028467725446233f,
                          0.38268343236508978f, 0.47139673682599764f, 0.55557023301960222f, 0.63439328416364549f};

// In-place 8-point DFT (DIF), natural order in/out: z[s] = sum_n z[n] W8^{ns}
__device__ __forceinline__ void dft8(cpx* z) {
    cpx e0 = z[0] + z[4], e1 = z[1] + z[5], e2 = z[2] + z[6], e3 = z[3] + z[7];
    cpx o0 = z[0] - z[4], o1 = z[1] - z[5], o2 = z[2] - z[6], o3 = z[3] - z[7];
    o1 = cmul(o1, cpx{RT2O2, -RT2O2});   // * W8^1
    o2 = mulni(o2);                       // * W8^2
    o3 = cmul(o3, cpx{-RT2O2, -RT2O2});  // * W8^3
    cpx a0 = e0 + e2, a1 = e1 + e3, b0 = e0 - e2, b1 = e1 - e3;
    z[0] = a0 + a1; z[4] = a0 - a1;
    z[2] = b0 + mulni(b1); z[6] = b0 + mulpi(b1);
    cpx c0 = o0 + o2, c1 = o1 + o3, d0 = o0 - o2, d1 = o1 - o3;
    z[1] = c0 + c1; z[5] = c0 - c1;
    z[3] = d0 + mulni(d1); z[7] = d0 + mulpi(d1);
}

// z[s] *= w1^s, s=1..7; powers via squaring tree (dep depth 3).
__device__ __forceinline__ void twiddle8(cpx* z, float theta) {
    float s_, c_;
    __sincosf(theta, &s_, &c_);
    cpx w1 = {c_, s_};
    cpx w2 = cmul(w1, w1), w3 = cmul(w1, w2), w4 = cmul(w2, w2);
    cpx w5 = cmul(w2, w3), w6 = cmul(w3, w3), w7 = cmul(w3, w4);
    z[1] = cmul(z[1], w1); z[2] = cmul(z[2], w2); z[3] = cmul(z[3], w3);
    z[4] = cmul(z[4], w4); z[5] = cmul(z[5], w5); z[6] = cmul(z[6], w6);
    z[7] = cmul(z[7], w7);
}

// base-8 3-digit reversal on [0,512)
__device__ __forceinline__ int R3(int x) { return ((x & 7) << 6) | (x & 56) | (x >> 6); }

// One row per 512-thread block. DST-II via N/2=4096 complex FFT, radices
// 8,8,8,8 (DIF over digits n = n0+8n1+64n2+512n3; k = u1+8u2+64u3+512u4):
//   v = Makhoul(sign*x); z[m] = v[2m] + i*v[2m+1]; Z = FFT_4096(z)
//   V[k] = Ze[k] + e^{-i pi k/4096} Zo[k]; out[8191-k] = Re(V[k] e^{-i pi k/16384})
// Stage positions in-place: idx = 512u1 + 64u2 + 8u3 + u4. S1-S3 are per-thread
// in-place (stride 512/64/8). S4: thread t handles block R3(t) (contiguous 8)
// so registers hold Z[t + 512 i] and output stores are wave-contiguous;
// Hermitian partner set Z[4096-k] lives in thread 512-t (write-back + read).
// 512 threads -> 4 blocks/CU x 8 waves = 32 waves/CU.
__global__ __launch_bounds__(THREADS) void dst_fft_kernel(const float* __restrict__ x,
                                                          float* __restrict__ out) {
    __shared__ __align__(16) cpx buf[4096];  // 32 KiB

    const int row = blockIdx.x;
    const float* __restrict__ xr = x + (size_t)row * 8192;
    float* __restrict__ yr = out + (size_t)row * 8192;
    const int t = threadIdx.x;

    cpx z[8];

    // ---- load in stage-1 butterfly order: m = t + 512u ----
    // m < 2048:  z = { x[4m],        x[4m+2]      }
    // m >= 2048: z = {-x[16383-4m], -x[16381-4m]  }
#pragma unroll
    for (int u = 0; u < 4; ++u) {
        float4 f = *reinterpret_cast<const float4*>(xr + 4 * t + 2048 * u);
        z[u] = {f.x, f.z};
    }
#pragma unroll
    for (int u = 4; u < 8; ++u) {
        float4 f = *reinterpret_cast<const float4*>(xr + (16380 - 4 * t - 2048 * u));
        z[u] = {-f.w, -f.y};
    }

    // ---- stage 1: radix-8 over n3 (stride 512), twiddle W4096^{t*u1} ----
    dft8(z);
    twiddle8(z, (-2.0f * PI_F / 4096.0f) * (float)t);
#pragma unroll
    for (int i = 0; i < 8; ++i) stb(buf, t + (i << 9), z[i]);
    __syncthreads();

    // ---- stage 2: radix-8 over n2 (stride 64), twiddle W512^{(t&63)*u2} ----
    const int b2 = ((t >> 6) << 9) | (t & 63);
#pragma unroll
    for (int i = 0; i < 8; ++i) z[i] = ldb(buf, b2 + (i << 6));
    dft8(z);
    twiddle8(z, (-2.0f * PI_F / 512.0f) * (float)(t & 63));
#pragma unroll
    for (int i = 0; i < 8; ++i) stb(buf, b2 + (i << 6), z[i]);
    __syncthreads();

    // ---- stage 3: radix-8 over n1 (stride 8), twiddle W64^{(t&7)*u3} ----
    const int b3 = ((t >> 6) << 9) | (((t >> 3) & 7) << 6) | (t & 7);
#pragma unroll
    for (int i = 0; i < 8; ++i) z[i] = ldb(buf, b3 + (i << 3));
    dft8(z);
    twiddle8(z, (-2.0f * PI_F / 64.0f) * (float)(t & 7));
#pragma unroll
    for (int i = 0; i < 8; ++i) stb(buf, b3 + (i << 3), z[i]);
    __syncthreads();

    // ---- stage 4: block R3(t), contiguous 8, no twiddle; RMW + write-back ----
    const int b4 = R3(t) << 3;
#pragma unroll
    for (int w = 0; w < 4; ++w) {
        float4 v = *reinterpret_cast<const float4*>(&buf[SW(b4 + 2 * w)]);
        z[2 * w] = {v.x, v.y};
        z[2 * w + 1] = {v.z, v.w};
    }
    dft8(z);  // z[i] = Z[t + 512 i], kept in registers
#pragma unroll
    for (int w = 0; w < 4; ++w) {
        *reinterpret_cast<float4*>(&buf[SW(b4 + 2 * w)]) =
            make_float4(z[2 * w].x, z[2 * w].y, z[2 * w + 1].x, z[2 * w + 1].y);
    }
    __syncthreads();

    // ---- epilogue: partner read + real-FFT unpack + DST twiddle ----
    float s4, c4, s1, c1;
    __sincosf((PI_F / 4096.0f) * (float)t, &s4, &c4);
    __sincosf((PI_F / 16384.0f) * (float)t, &s1, &c1);
    const cpx w4 = {c4, -s4};  // e^{-i pi t/4096}
    const cpx w1 = {c1, s1};   // {cos, sin}(pi t/16384)

    // emit outputs for k = t + 512 i given Z1 = Z[k], Z2 = Z[4096-k]
    auto emit = [&](int i, cpx Z1, cpx Z2, bool writeLow) {
        const int k = t + (i << 9);
        cpx Ze = 0.5f * cpx{Z1.x + Z2.x, Z1.y - Z2.y};
        cpx Zo = 0.5f * cpx{Z1.y + Z2.y, Z2.x - Z1.x};
        cpx w4s = cmul(w4, cpx{C8[i], -S8[i]});
        cpx w1s = cmul(w1, cpx{C32[i], S32[i]});
        cpx V = Ze + cmul(w4s, Zo);
        yr[8191 - k] = fmaf(V.x, w1s.x, V.y * w1s.y);
        if (writeLow) yr[k - 1] = fmaf(V.x, w1s.y, -V.y * w1s.x);
    };

    if (t == 0) {
        // self-paired set: k = 512 i; partner reg (8-i)&7
#pragma unroll
        for (int i = 0; i < 8; ++i) emit(i, z[i], z[(8 - i) & 7], i > 0);
        yr[4095] = (z[0].x - z[0].y) * RT2O2;  // k = 4096 term
    } else {
        const int pb = R3(512 - t) << 3;
        // partner reg j' holds Z[(512-t) + 512 j']; pairing j' = 7 - i.
#pragma unroll
        for (int w = 0; w < 4; ++w) {
            float4 v = *reinterpret_cast<const float4*>(&buf[SW(pb + 2 * w)]);
            emit(7 - 2 * w, z[7 - 2 * w], cpx{v.x, v.y}, true);  // j' = 2w
            emit(6 - 2 * w, z[6 - 2 * w], cpx{v.z, v.w}, true);  // j' = 2w+1
        }
    }
}

extern "C" void kernel_launch(void* const* d_in, const int* in_sizes, int n_in,
                              void* d_out, int out_size, void* d_ws, size_t ws_size,
                              hipStream_t stream) {
    const float* x = (const float*)d_in[0];
    float* out = (float*)d_out;
    const int rows = in_sizes[0] / 8192;  // 4096
    dst_fft_kernel<<<rows, THREADS, 0, stream>>>(x, out);
}